// Round 12
// baseline (183.173 us; speedup 1.0000x reference)
//
#include <hip/hip_runtime.h>

// out[N,256] = concat( x[N,128] @ Wx[128,128] + bx,
//                      segsum(edge_attr by src)[N,32] @ We[32,128] + be )
//
// Pipeline:
//   prep:  Wx^T, We^T -> bf16 in ws (read as B-frags straight from L2)
//   binA:  bucket packed (edge_id<<7 | node&127) by src>>7 (128-node buckets)
//   fused: per bucket: CSR build in LDS -> register gather (4 thr/node,
//          8 loads in flight) -> hx MFMA -> barrier -> he MFMA.
//          LDS ~24 KB -> 4 blocks/CU (max waves) for gather latency hiding.

#define BSHIFT    7
#define BSIZE     128
#define NBMAX     1024
#define SEG_CAP   3584    // pairs per bucket (mean ~2046, sigma ~45, +34 sigma)
#define POOL_SZ   3648
#define CHUNK_A   8192
#define SPILL_CAP 65536

typedef short bf16x8 __attribute__((ext_vector_type(8)));
typedef float f32x4  __attribute__((ext_vector_type(4)));

__device__ __forceinline__ unsigned short f2bf(float f) {
    union { float f; unsigned u; } c; c.f = f;
    unsigned u = c.u;
    u += 0x7FFF + ((u >> 16) & 1);          // round-to-nearest-even
    return (unsigned short)(u >> 16);
}

__device__ __forceinline__ void acc4(float4& a, const float4 v) {
    a.x += v.x; a.y += v.y; a.z += v.z; a.w += v.w;
}

// ---------- prep: transposed bf16 weights into ws ----------
__global__ __launch_bounds__(256) void prep_kernel(
    const float* __restrict__ Wx, const float* __restrict__ We,
    unsigned short* __restrict__ WxT, unsigned short* __restrict__ WeT)
{
    int t = blockIdx.x * 256 + threadIdx.x;
    if (t < 128 * 128) {
        int j = t >> 7, k = t & 127;
        WxT[j * 128 + k] = f2bf(Wx[k * 128 + j]);   // [j][k], 256B rows
    }
    if (t < 128 * 32) {
        int j = t >> 5, k = t & 31;
        WeT[j * 32 + k] = f2bf(We[k * 128 + j]);    // [j][k], 64B rows
    }
}

// ---------- Pass A: bucket edges (packed 4B pairs) ----------
__global__ __launch_bounds__(512) void binA_kernel(
    const int* __restrict__ src, int E, int nb,
    unsigned* __restrict__ segs, int* __restrict__ gcnt,
    int2* __restrict__ spill, int* __restrict__ spillcnt)
{
    __shared__ unsigned pool[CHUNK_A];      // 32 KB
    __shared__ int hist[NBMAX];
    __shared__ int offs[NBMAX];
    __shared__ int lcur[NBMAX];
    __shared__ int gbase[NBMAX];
    __shared__ int gallow[NBMAX];
    __shared__ int wsum[8];

    int tid = threadIdx.x;
    int base = blockIdx.x * CHUNK_A;

    for (int i = tid; i < NBMAX; i += 512) hist[i] = 0;
    __syncthreads();

    // count pass; cache src values in registers for the place pass
    int srcv[CHUNK_A / 512];
    #pragma unroll
    for (int u = 0; u < CHUNK_A / 512; ++u) {
        int e = base + tid + u * 512;
        int s = (e < E) ? src[e] : -1;
        srcv[u] = s;
        if (s >= 0) atomicAdd(&hist[s >> BSHIFT], 1);
    }
    __syncthreads();

    // block exclusive scan: each thread owns buckets 2t, 2t+1
    {
        int t2 = tid * 2;
        int c0 = hist[t2], c1 = hist[t2 + 1];
        int s = c0 + c1;
        int lane = tid & 63, wid = tid >> 6;
        int ws = s;
        #pragma unroll
        for (int d = 1; d < 64; d <<= 1) {
            int t = __shfl_up(ws, d);
            if (lane >= d) ws += t;
        }
        if (lane == 63) wsum[wid] = ws;
        __syncthreads();
        int woff = 0;
        #pragma unroll
        for (int w = 0; w < 8; ++w) if (w < wid) woff += wsum[w];
        int ex = woff + ws - s;
        offs[t2] = ex;          lcur[t2] = ex;
        offs[t2 + 1] = ex + c0; lcur[t2 + 1] = ex + c0;
    }
    __syncthreads();

    // reserve global segment space
    {
        int t2 = tid * 2;
        #pragma unroll
        for (int u = 0; u < 2; ++u) {
            int b = t2 + u;
            if (b < nb) {
                int cnt = hist[b];
                int b0 = cnt ? atomicAdd(&gcnt[b], cnt) : 0;
                gbase[b] = b0;
                int allow = SEG_CAP - b0;
                if (allow < 0) allow = 0;
                if (allow > cnt) allow = cnt;
                gallow[b] = allow;
            }
        }
    }
    __syncthreads();

    // place packed pairs into LDS pool grouped by bucket (src from registers)
    #pragma unroll
    for (int u = 0; u < CHUNK_A / 512; ++u) {
        int s = srcv[u];
        if (s >= 0) {
            int e = base + tid + u * 512;
            int b = s >> BSHIFT;
            int p = atomicAdd(&lcur[b], 1);
            pool[p] = ((unsigned)e << BSHIFT) | (unsigned)(s & (BSIZE - 1));
        }
    }
    __syncthreads();

    // coalesced flush: wave w handles buckets w, w+8, ...
    int wid = tid >> 6, lane = tid & 63;
    for (int b = wid; b < nb; b += 8) {
        int cnt = hist[b];
        int off = offs[b];
        int allow = gallow[b];
        unsigned* dst = segs + (size_t)b * SEG_CAP + gbase[b];
        for (int i = lane; i < allow; i += 64)
            dst[i] = pool[off + i];
        int excess = cnt - allow;
        if (excess > 0) {                 // never in practice
            int sb;
            if (lane == 0) sb = atomicAdd(spillcnt, excess);
            sb = __shfl(sb, 0);
            for (int i = lane; i < excess; i += 64) {
                int sp = sb + i;
                if (sp < SPILL_CAP) {
                    unsigned pv = pool[off + allow + i];
                    spill[sp] = make_int2((int)(pv >> BSHIFT),
                                          (b << BSHIFT) | (int)(pv & (BSIZE - 1)));
                }
            }
        }
    }
}

// ---------- fused: CSR build + gather + hx MFMA + he MFMA (slim LDS) ----------
__global__ __launch_bounds__(512, 8) void fused_kernel(
    const unsigned* __restrict__ segs, const int* __restrict__ gcnt,
    const int2* __restrict__ spill, const int* __restrict__ spillcnt,
    const float4* __restrict__ ea4, const float* __restrict__ x,
    const unsigned short* __restrict__ wxt, const float* __restrict__ bx,
    const unsigned short* __restrict__ wet, const float* __restrict__ be,
    float* __restrict__ out, int N)
{
    __shared__ int counts[BSIZE];
    __shared__ int starts[BSIZE + 1];
    __shared__ int cursor[BSIZE];
    __shared__ int pool[POOL_SZ];       // 14.3 KB edge ids
    __shared__ char sAgg[BSIZE * 64];   // agg tile bf16 swizzled, 8 KB

    int tid = threadIdx.x;
    int b = blockIdx.x;
    int node0 = b << BSHIFT;
    int lane = tid & 63, w = tid >> 6;
    int col = lane & 15, m = lane >> 4;

    if (tid < BSIZE) counts[tid] = 0;
    __syncthreads();

    int segn = gcnt[b]; if (segn > SEG_CAP) segn = SEG_CAP;
    const unsigned* seg = segs + (size_t)b * SEG_CAP;
    int nsp = *spillcnt; if (nsp > SPILL_CAP) nsp = SPILL_CAP;

    // count
    for (int i = tid; i < segn; i += 512)
        atomicAdd(&counts[seg[i] & (BSIZE - 1)], 1);
    if (nsp)
        for (int i = tid; i < nsp; i += 512) {
            int2 p = spill[i];
            if ((p.y >> BSHIFT) == b) atomicAdd(&counts[p.y & (BSIZE - 1)], 1);
        }
    __syncthreads();

    // exclusive scan over 128 counters (wave 0, 2 per lane)
    if (tid < 64) {
        int c0 = counts[tid * 2], c1 = counts[tid * 2 + 1];
        int s = c0 + c1;
        int ws = s;
        #pragma unroll
        for (int d = 1; d < 64; d <<= 1) {
            int t = __shfl_up(ws, d);
            if (tid >= d) ws += t;
        }
        int ex = ws - s;
        starts[tid * 2] = ex;          cursor[tid * 2] = ex;
        starts[tid * 2 + 1] = ex + c0; cursor[tid * 2 + 1] = ex + c0;
        if (tid == 63) starts[BSIZE] = ws;
    }
    __syncthreads();

    // fill grouped edge-id pool
    for (int i = tid; i < segn; i += 512) {
        unsigned pe = seg[i];
        int pos = atomicAdd(&cursor[pe & (BSIZE - 1)], 1);
        if (pos < POOL_SZ) pool[pos] = (int)(pe >> BSHIFT);
    }
    if (nsp)
        for (int i = tid; i < nsp; i += 512) {
            int2 p = spill[i];
            if ((p.y >> BSHIFT) == b) {
                int pos = atomicAdd(&cursor[p.y & (BSIZE - 1)], 1);
                if (pos < POOL_SZ) pool[pos] = p.x;
            }
        }
    __syncthreads();

    // per-node register gather: 4 threads/node, quads q2 and q2+4,
    // 4-deep unroll => 8 independent 16B loads in flight per thread.
    // (4 consecutive lanes cover a full 64B line per instruction.)
    {
        int g = tid >> 2, q2 = tid & 3;
        int node = node0 + g;
        float4 aL0 = {0.f,0.f,0.f,0.f}, aL1 = {0.f,0.f,0.f,0.f};
        float4 aH0 = {0.f,0.f,0.f,0.f}, aH1 = {0.f,0.f,0.f,0.f};
        if (node < N) {
            int p0 = starts[g], p1 = starts[g + 1];
            if (p1 > POOL_SZ) p1 = POOL_SZ;
            int p = p0;
            for (; p + 4 <= p1; p += 4) {
                int e0 = pool[p], e1 = pool[p + 1], e2 = pool[p + 2], e3 = pool[p + 3];
                const float4* r0 = ea4 + (size_t)e0 * 8;
                const float4* r1 = ea4 + (size_t)e1 * 8;
                const float4* r2 = ea4 + (size_t)e2 * 8;
                const float4* r3 = ea4 + (size_t)e3 * 8;
                float4 l0 = r0[q2],     l1 = r1[q2],     l2 = r2[q2],     l3 = r3[q2];
                float4 h0 = r0[q2 + 4], h1 = r1[q2 + 4], h2 = r2[q2 + 4], h3 = r3[q2 + 4];
                acc4(aL0, l0); acc4(aL1, l1); acc4(aH0, h0); acc4(aH1, h1);
                acc4(aL0, l2); acc4(aL1, l3); acc4(aH0, h2); acc4(aH1, h3);
            }
            for (; p < p1; ++p) {
                const float4* r = ea4 + (size_t)pool[p] * 8;
                float4 l = r[q2], h = r[q2 + 4];
                acc4(aL0, l); acc4(aH0, h);
            }
            acc4(aL0, aL1); acc4(aH0, aH1);
        }
        // write agg rows into swizzled LDS (zeros for out-of-range nodes)
        uint2 lo, hi;
        lo.x = (unsigned)f2bf(aL0.x) | ((unsigned)f2bf(aL0.y) << 16);
        lo.y = (unsigned)f2bf(aL0.z) | ((unsigned)f2bf(aL0.w) << 16);
        hi.x = (unsigned)f2bf(aH0.x) | ((unsigned)f2bf(aH0.y) << 16);
        hi.y = (unsigned)f2bf(aH0.z) | ((unsigned)f2bf(aH0.w) << 16);
        int swz = (g & 7) << 4;
        *(uint2*)(sAgg + ((g * 64 + q2 * 8) ^ swz))       = lo;
        *(uint2*)(sAgg + ((g * 64 + (q2 + 4) * 8) ^ swz)) = hi;
    }

    // ---- hx GEMM: A-frags from global x, B-frags from global WxT (L2-hot)
    int lrow = (w << 4) + col;
    int grow = node0 + lrow;
    bool rok = grow < N;
    int srow = node0 + (w << 4) + m * 4;

    {
        const float* xr = x + (size_t)grow * 128 + m * 8;
        bf16x8 ax[4];
        #pragma unroll
        for (int kk = 0; kk < 4; ++kk) {
            float4 p0 = {0.f,0.f,0.f,0.f}, p1 = {0.f,0.f,0.f,0.f};
            if (rok) {
                p0 = *(const float4*)(xr + kk * 32);
                p1 = *(const float4*)(xr + kk * 32 + 4);
            }
            bf16x8 a;
            a[0] = (short)f2bf(p0.x); a[1] = (short)f2bf(p0.y);
            a[2] = (short)f2bf(p0.z); a[3] = (short)f2bf(p0.w);
            a[4] = (short)f2bf(p1.x); a[5] = (short)f2bf(p1.y);
            a[6] = (short)f2bf(p1.z); a[7] = (short)f2bf(p1.w);
            ax[kk] = a;
        }

        #pragma unroll
        for (int half = 0; half < 2; ++half) {
            f32x4 acc[4];
            #pragma unroll
            for (int ct = 0; ct < 4; ++ct) {
                int c8 = half * 4 + ct;
                float bv = bx[c8 * 16 + col];
                acc[ct] = (f32x4){bv, bv, bv, bv};
            }
            #pragma unroll
            for (int ct = 0; ct < 4; ++ct) {
                int c8 = half * 4 + ct;
                const unsigned short* brow = wxt + (size_t)(c8 * 16 + col) * 128;
                #pragma unroll
                for (int kk = 0; kk < 4; ++kk) {
                    bf16x8 bfrag = *(const bf16x8*)(brow + kk * 32 + m * 8);
                    acc[ct] = __builtin_amdgcn_mfma_f32_16x16x32_bf16(ax[kk], bfrag, acc[ct], 0, 0, 0);
                }
            }
            #pragma unroll
            for (int r = 0; r < 4; ++r) {
                if (srow + r < N) {
                    float* orow = out + (size_t)(srow + r) * 256 + col + half * 64;
                    #pragma unroll
                    for (int ct = 0; ct < 4; ++ct)
                        orow[ct * 16] = acc[ct][r];
                }
            }
        }
    }

    __syncthreads();    // sAgg complete

    // ---- he GEMM: [128,32] @ We + be -> out[:,128:256]
    {
        bf16x8 aa = *(const bf16x8*)(sAgg + ((lrow * 64 + m * 16) ^ ((lrow & 7) << 4)));

        f32x4 acc[8];
        #pragma unroll
        for (int ct = 0; ct < 8; ++ct) {
            float bv = be[ct * 16 + col];
            acc[ct] = (f32x4){bv, bv, bv, bv};
        }
        #pragma unroll
        for (int ct = 0; ct < 8; ++ct) {
            bf16x8 bwe = *(const bf16x8*)(wet + (size_t)(ct * 16 + col) * 32 + m * 8);
            acc[ct] = __builtin_amdgcn_mfma_f32_16x16x32_bf16(aa, bwe, acc[ct], 0, 0, 0);
        }

        #pragma unroll
        for (int r = 0; r < 4; ++r) {
            if (srow + r < N) {
                float* orow = out + (size_t)(srow + r) * 256 + 128 + col;
                #pragma unroll
                for (int ct = 0; ct < 8; ++ct)
                    orow[ct * 16] = acc[ct][r];
            }
        }
    }
}

// ---------- fallback: atomic scatter + convert + full GEMM ----------
__global__ __launch_bounds__(256) void scatter_kernel(
    const float4* __restrict__ ea4, const int* __restrict__ src,
    float* __restrict__ agg, int nquads)
{
    int t = blockIdx.x * blockDim.x + threadIdx.x;
    if (t >= nquads) return;
    int e = t >> 3, q = t & 7;
    float4 v = ea4[t];
    int node = src[e];
    float* dst = agg + (size_t)node * 32 + q * 4;
    atomicAdd(dst + 0, v.x); atomicAdd(dst + 1, v.y);
    atomicAdd(dst + 2, v.z); atomicAdd(dst + 3, v.w);
}

__global__ __launch_bounds__(256) void cvt_kernel(
    const float* __restrict__ agg, unsigned short* __restrict__ aggbf, int n)
{
    int t = blockIdx.x * blockDim.x + threadIdx.x;
    if (t < n) aggbf[t] = f2bf(agg[t]);
}

__global__ __launch_bounds__(512, 4) void mfma_gemm_full(
    const float* __restrict__ x, const unsigned short* __restrict__ aggbf,
    const float* __restrict__ Wx, const float* __restrict__ bx,
    const float* __restrict__ We, const float* __restrict__ be,
    float* __restrict__ out, int N, int ntiles)
{
    __shared__ char sWxT[128 * 256];
    __shared__ char sWeT[128 * 64];
    __shared__ char sX[128 * 256];
    __shared__ char sA[128 * 64];

    int tid = threadIdx.x;
    int lane = tid & 63, w = tid >> 6;
    int col = lane & 15, m = lane >> 4;

    for (int i = tid; i < 128 * 128; i += 512) {
        int k = i >> 7, j = i & 127;
        *(unsigned short*)(sWxT + j * 256 + ((k * 2) ^ ((j & 7) << 4))) = f2bf(Wx[i]);
    }
    for (int i = tid; i < 32 * 128; i += 512) {
        int k = i >> 7, j = i & 127;
        *(unsigned short*)(sWeT + j * 64 + ((k * 2) ^ ((j & 3) << 4))) = f2bf(We[i]);
    }
    float bxv[8], bev[8];
    #pragma unroll
    for (int ct = 0; ct < 8; ++ct) {
        bxv[ct] = bx[ct * 16 + col];
        bev[ct] = be[ct * 16 + col];
    }

    int lrow = (w << 4) + col;
    int swzA = (lrow & 7) << 4;

    for (int t = blockIdx.x; t < ntiles; t += gridDim.x) {
        int rbase_t = t << 7;
        __syncthreads();

        for (int i = tid; i < 128 * 32; i += 512) {
            int row = i >> 5, c4 = i & 31;
            int gr = rbase_t + row;
            float4 v = {0.f, 0.f, 0.f, 0.f};
            if (gr < N) v = *(const float4*)(x + (size_t)gr * 128 + c4 * 4);
            uint2 uu;
            uu.x = (unsigned)f2bf(v.x) | ((unsigned)f2bf(v.y) << 16);
            uu.y = (unsigned)f2bf(v.z) | ((unsigned)f2bf(v.w) << 16);
            *(uint2*)(sX + ((row * 256 + c4 * 8) ^ ((row & 7) << 4))) = uu;
        }
        {
            int row = tid >> 2, mm = tid & 3;
            int gr = rbase_t + row;
            bf16x8 av = {0, 0, 0, 0, 0, 0, 0, 0};
            if (gr < N) av = *(const bf16x8*)(aggbf + (size_t)gr * 32 + mm * 8);
            *(bf16x8*)(sA + ((row * 64 + mm * 16) ^ ((row & 7) << 4))) = av;
        }
        __syncthreads();

        bf16x8 ax[4];
        #pragma unroll
        for (int kk = 0; kk < 4; ++kk)
            ax[kk] = *(const bf16x8*)(sX + lrow * 256 + ((kk * 64 + m * 16) ^ swzA));
        bf16x8 aa = *(const bf16x8*)(sA + ((lrow * 64 + m * 16) ^ swzA));

        int srow = rbase_t + (w << 4) + m * 4;

        #pragma unroll
        for (int half = 0; half < 2; ++half) {
            f32x4 acc[8];
            #pragma unroll
            for (int ct = 0; ct < 4; ++ct) {
                int c8 = half * 4 + ct;
                acc[ct]     = (f32x4){bxv[c8], bxv[c8], bxv[c8], bxv[c8]};
                acc[4 + ct] = (f32x4){bev[c8], bev[c8], bev[c8], bev[c8]};
            }
            #pragma unroll
            for (int ct = 0; ct < 4; ++ct) {
                int c8 = half * 4 + ct;
                const char* brow = sWxT + (c8 * 16 + col) * 256;
                int swz = (col & 7) << 4;
                #pragma unroll
                for (int kk = 0; kk < 4; ++kk) {
                    bf16x8 bfrag = *(const bf16x8*)(brow + ((kk * 64 + m * 16) ^ swz));
                    acc[ct] = __builtin_amdgcn_mfma_f32_16x16x32_bf16(ax[kk], bfrag, acc[ct], 0, 0, 0);
                }
                bf16x8 bwe = *(const bf16x8*)(sWeT + (c8 * 16 + col) * 64 + ((m * 16) ^ ((col & 3) << 4)));
                acc[4 + ct] = __builtin_amdgcn_mfma_f32_16x16x32_bf16(aa, bwe, acc[4 + ct], 0, 0, 0);
            }
            #pragma unroll
            for (int r = 0; r < 4; ++r) {
                if (srow + r < N) {
                    float* orow = out + (size_t)(srow + r) * 256 + col + half * 64;
                    #pragma unroll
                    for (int ct = 0; ct < 4; ++ct) {
                        orow[ct * 16]       = acc[ct][r];
                        orow[128 + ct * 16] = acc[4 + ct][r];
                    }
                }
            }
        }
    }
}

extern "C" void kernel_launch(void* const* d_in, const int* in_sizes, int n_in,
                              void* d_out, int out_size, void* d_ws, size_t ws_size,
                              hipStream_t stream) {
    const float* x          = (const float*)d_in[0];
    const int*   edge_index = (const int*)d_in[1];   // [2,E] flat; row 0 = src
    const float* edge_attr  = (const float*)d_in[2];
    const float* Wx         = (const float*)d_in[3];
    const float* bx         = (const float*)d_in[4];
    const float* We         = (const float*)d_in[5];
    const float* be         = (const float*)d_in[6];
    float* out = (float*)d_out;

    int N = in_sizes[0] / 128;
    int E = in_sizes[2] / 32;
    int nb = (N + BSIZE - 1) >> BSHIFT;
    int ntiles = (N + 127) >> 7;

    char* ws = (char*)d_ws;
    size_t wxtBytes   = 128 * 128 * 2;               // 32 KB
    size_t wetBytes   = 128 * 32 * 2;                // 8 KB
    size_t aggbfBytes = ((size_t)N * 32 * 2 + 255) & ~255ull;
    size_t segsBytes  = ((size_t)nb * SEG_CAP * 4 + 255) & ~255ull;
    size_t gcntBytes  = ((size_t)(nb + 1) * 4 + 255) & ~255ull;
    size_t spillBytes = (size_t)SPILL_CAP * 8;
    size_t need = wxtBytes + wetBytes + aggbfBytes + segsBytes + gcntBytes + spillBytes;

    unsigned short* wxt   = (unsigned short*)ws;
    unsigned short* wet   = (unsigned short*)(ws + wxtBytes);
    unsigned short* aggbf = (unsigned short*)(ws + wxtBytes + wetBytes);

    if (ws_size >= need && nb <= NBMAX) {
        char* p = ws + wxtBytes + wetBytes + aggbfBytes;
        unsigned* segs  = (unsigned*)p;
        int* gcnt       = (int*)(p + segsBytes);
        int* spillcnt   = gcnt + nb;
        int2* spill     = (int2*)(p + segsBytes + gcntBytes);

        hipMemsetAsync(gcnt, 0, (size_t)(nb + 1) * 4, stream);
        prep_kernel<<<64, 256, 0, stream>>>(Wx, We, wxt, wet);
        int nblkA = (E + CHUNK_A - 1) / CHUNK_A;
        binA_kernel<<<nblkA, 512, 0, stream>>>(edge_index, E, nb, segs, gcnt, spill, spillcnt);
        fused_kernel<<<nb, 512, 0, stream>>>(segs, gcnt, spill, spillcnt,
                                             (const float4*)edge_attr, x,
                                             wxt, bx, wet, be, out, N);
    } else {
        float* aggf = (float*)(ws + wxtBytes + wetBytes + aggbfBytes);
        hipMemsetAsync(aggf, 0, (size_t)N * 32 * 4, stream);
        int nq = E * 8;
        scatter_kernel<<<(nq + 255) / 256, 256, 0, stream>>>(
            (const float4*)edge_attr, edge_index, aggf, nq);
        cvt_kernel<<<(N * 32 + 255) / 256, 256, 0, stream>>>(aggf, aggbf, N * 32);
        int g = ntiles < 512 ? ntiles : 512;
        mfma_gemm_full<<<g, 512, 0, stream>>>(x, aggbf, Wx, bx, We, be, out, N, ntiles);
    }
}

// Round 13
// 161.051 us; speedup vs baseline: 1.1374x; 1.1374x over previous
//
#include <hip/hip_runtime.h>

// out[N,256] = concat( x[N,128] @ Wx[128,128] + bx,
//                      segsum(edge_attr by src)[N,32] @ We[32,128] + be )
//
// Pipeline:
//   prep:  Wx^T, We^T -> bf16 in ws (read as B-frags straight from L2)
//   binA:  bucket packed (edge_id<<7 | node&127) by src>>7 (128-node buckets)
//   fused: per bucket: CSR build in LDS -> register gather (4 thr/node,
//          8 loads in flight) -> hx MFMA -> barrier -> he MFMA.
//          LDS ~24 KB; launch_bounds(512,4) -> VGPR<=128 (no spill),
//          natural ~56-64 VGPR allows 4 blocks/CU.

#define BSHIFT    7
#define BSIZE     128
#define NBMAX     1024
#define SEG_CAP   3584    // pairs per bucket (mean ~2046, sigma ~45, +34 sigma)
#define POOL_SZ   3648
#define CHUNK_A   8192
#define SPILL_CAP 65536

typedef short bf16x8 __attribute__((ext_vector_type(8)));
typedef float f32x4  __attribute__((ext_vector_type(4)));

__device__ __forceinline__ unsigned short f2bf(float f) {
    union { float f; unsigned u; } c; c.f = f;
    unsigned u = c.u;
    u += 0x7FFF + ((u >> 16) & 1);          // round-to-nearest-even
    return (unsigned short)(u >> 16);
}

__device__ __forceinline__ void acc4(float4& a, const float4 v) {
    a.x += v.x; a.y += v.y; a.z += v.z; a.w += v.w;
}

// ---------- prep: transposed bf16 weights into ws ----------
__global__ __launch_bounds__(256) void prep_kernel(
    const float* __restrict__ Wx, const float* __restrict__ We,
    unsigned short* __restrict__ WxT, unsigned short* __restrict__ WeT)
{
    int t = blockIdx.x * 256 + threadIdx.x;
    if (t < 128 * 128) {
        int j = t >> 7, k = t & 127;
        WxT[j * 128 + k] = f2bf(Wx[k * 128 + j]);   // [j][k], 256B rows
    }
    if (t < 128 * 32) {
        int j = t >> 5, k = t & 31;
        WeT[j * 32 + k] = f2bf(We[k * 128 + j]);    // [j][k], 64B rows
    }
}

// ---------- Pass A: bucket edges (packed 4B pairs) ----------
__global__ __launch_bounds__(512) void binA_kernel(
    const int* __restrict__ src, int E, int nb,
    unsigned* __restrict__ segs, int* __restrict__ gcnt,
    int2* __restrict__ spill, int* __restrict__ spillcnt)
{
    __shared__ unsigned pool[CHUNK_A];      // 32 KB
    __shared__ int hist[NBMAX];
    __shared__ int offs[NBMAX];
    __shared__ int lcur[NBMAX];
    __shared__ int gbase[NBMAX];
    __shared__ int gallow[NBMAX];
    __shared__ int wsum[8];

    int tid = threadIdx.x;
    int base = blockIdx.x * CHUNK_A;

    for (int i = tid; i < NBMAX; i += 512) hist[i] = 0;
    __syncthreads();

    // count pass; cache src values in registers for the place pass
    int srcv[CHUNK_A / 512];
    #pragma unroll
    for (int u = 0; u < CHUNK_A / 512; ++u) {
        int e = base + tid + u * 512;
        int s = (e < E) ? src[e] : -1;
        srcv[u] = s;
        if (s >= 0) atomicAdd(&hist[s >> BSHIFT], 1);
    }
    __syncthreads();

    // block exclusive scan: each thread owns buckets 2t, 2t+1
    {
        int t2 = tid * 2;
        int c0 = hist[t2], c1 = hist[t2 + 1];
        int s = c0 + c1;
        int lane = tid & 63, wid = tid >> 6;
        int ws = s;
        #pragma unroll
        for (int d = 1; d < 64; d <<= 1) {
            int t = __shfl_up(ws, d);
            if (lane >= d) ws += t;
        }
        if (lane == 63) wsum[wid] = ws;
        __syncthreads();
        int woff = 0;
        #pragma unroll
        for (int w = 0; w < 8; ++w) if (w < wid) woff += wsum[w];
        int ex = woff + ws - s;
        offs[t2] = ex;          lcur[t2] = ex;
        offs[t2 + 1] = ex + c0; lcur[t2 + 1] = ex + c0;
    }
    __syncthreads();

    // reserve global segment space
    {
        int t2 = tid * 2;
        #pragma unroll
        for (int u = 0; u < 2; ++u) {
            int b = t2 + u;
            if (b < nb) {
                int cnt = hist[b];
                int b0 = cnt ? atomicAdd(&gcnt[b], cnt) : 0;
                gbase[b] = b0;
                int allow = SEG_CAP - b0;
                if (allow < 0) allow = 0;
                if (allow > cnt) allow = cnt;
                gallow[b] = allow;
            }
        }
    }
    __syncthreads();

    // place packed pairs into LDS pool grouped by bucket (src from registers)
    #pragma unroll
    for (int u = 0; u < CHUNK_A / 512; ++u) {
        int s = srcv[u];
        if (s >= 0) {
            int e = base + tid + u * 512;
            int b = s >> BSHIFT;
            int p = atomicAdd(&lcur[b], 1);
            pool[p] = ((unsigned)e << BSHIFT) | (unsigned)(s & (BSIZE - 1));
        }
    }
    __syncthreads();

    // coalesced flush: wave w handles buckets w, w+8, ...
    int wid = tid >> 6, lane = tid & 63;
    for (int b = wid; b < nb; b += 8) {
        int cnt = hist[b];
        int off = offs[b];
        int allow = gallow[b];
        unsigned* dst = segs + (size_t)b * SEG_CAP + gbase[b];
        for (int i = lane; i < allow; i += 64)
            dst[i] = pool[off + i];
        int excess = cnt - allow;
        if (excess > 0) {                 // never in practice
            int sb;
            if (lane == 0) sb = atomicAdd(spillcnt, excess);
            sb = __shfl(sb, 0);
            for (int i = lane; i < excess; i += 64) {
                int sp = sb + i;
                if (sp < SPILL_CAP) {
                    unsigned pv = pool[off + allow + i];
                    spill[sp] = make_int2((int)(pv >> BSHIFT),
                                          (b << BSHIFT) | (int)(pv & (BSIZE - 1)));
                }
            }
        }
    }
}

// ---------- fused: CSR build + gather + hx MFMA + he MFMA (slim LDS) ----------
__global__ __launch_bounds__(512, 4) void fused_kernel(
    const unsigned* __restrict__ segs, const int* __restrict__ gcnt,
    const int2* __restrict__ spill, const int* __restrict__ spillcnt,
    const float4* __restrict__ ea4, const float* __restrict__ x,
    const unsigned short* __restrict__ wxt, const float* __restrict__ bx,
    const unsigned short* __restrict__ wet, const float* __restrict__ be,
    float* __restrict__ out, int N)
{
    __shared__ int counts[BSIZE];
    __shared__ int starts[BSIZE + 1];
    __shared__ int cursor[BSIZE];
    __shared__ int pool[POOL_SZ];       // 14.3 KB edge ids
    __shared__ char sAgg[BSIZE * 64];   // agg tile bf16 swizzled, 8 KB

    int tid = threadIdx.x;
    int b = blockIdx.x;
    int node0 = b << BSHIFT;
    int lane = tid & 63, w = tid >> 6;
    int col = lane & 15, m = lane >> 4;

    if (tid < BSIZE) counts[tid] = 0;
    __syncthreads();

    int segn = gcnt[b]; if (segn > SEG_CAP) segn = SEG_CAP;
    const unsigned* seg = segs + (size_t)b * SEG_CAP;
    int nsp = *spillcnt; if (nsp > SPILL_CAP) nsp = SPILL_CAP;

    // count
    for (int i = tid; i < segn; i += 512)
        atomicAdd(&counts[seg[i] & (BSIZE - 1)], 1);
    if (nsp)
        for (int i = tid; i < nsp; i += 512) {
            int2 p = spill[i];
            if ((p.y >> BSHIFT) == b) atomicAdd(&counts[p.y & (BSIZE - 1)], 1);
        }
    __syncthreads();

    // exclusive scan over 128 counters (wave 0, 2 per lane)
    if (tid < 64) {
        int c0 = counts[tid * 2], c1 = counts[tid * 2 + 1];
        int s = c0 + c1;
        int ws = s;
        #pragma unroll
        for (int d = 1; d < 64; d <<= 1) {
            int t = __shfl_up(ws, d);
            if (tid >= d) ws += t;
        }
        int ex = ws - s;
        starts[tid * 2] = ex;          cursor[tid * 2] = ex;
        starts[tid * 2 + 1] = ex + c0; cursor[tid * 2 + 1] = ex + c0;
        if (tid == 63) starts[BSIZE] = ws;
    }
    __syncthreads();

    // fill grouped edge-id pool
    for (int i = tid; i < segn; i += 512) {
        unsigned pe = seg[i];
        int pos = atomicAdd(&cursor[pe & (BSIZE - 1)], 1);
        if (pos < POOL_SZ) pool[pos] = (int)(pe >> BSHIFT);
    }
    if (nsp)
        for (int i = tid; i < nsp; i += 512) {
            int2 p = spill[i];
            if ((p.y >> BSHIFT) == b) {
                int pos = atomicAdd(&cursor[p.y & (BSIZE - 1)], 1);
                if (pos < POOL_SZ) pool[pos] = p.x;
            }
        }
    __syncthreads();

    // per-node register gather: 4 threads/node, quads q2 and q2+4,
    // 4-deep unroll => 8 independent 16B loads in flight per thread.
    // (4 consecutive lanes cover a full 64B line per instruction.)
    {
        int g = tid >> 2, q2 = tid & 3;
        int node = node0 + g;
        float4 aL0 = {0.f,0.f,0.f,0.f}, aL1 = {0.f,0.f,0.f,0.f};
        float4 aH0 = {0.f,0.f,0.f,0.f}, aH1 = {0.f,0.f,0.f,0.f};
        if (node < N) {
            int p0 = starts[g], p1 = starts[g + 1];
            if (p1 > POOL_SZ) p1 = POOL_SZ;
            int p = p0;
            for (; p + 4 <= p1; p += 4) {
                int e0 = pool[p], e1 = pool[p + 1], e2 = pool[p + 2], e3 = pool[p + 3];
                const float4* r0 = ea4 + (size_t)e0 * 8;
                const float4* r1 = ea4 + (size_t)e1 * 8;
                const float4* r2 = ea4 + (size_t)e2 * 8;
                const float4* r3 = ea4 + (size_t)e3 * 8;
                float4 l0 = r0[q2],     l1 = r1[q2],     l2 = r2[q2],     l3 = r3[q2];
                float4 h0 = r0[q2 + 4], h1 = r1[q2 + 4], h2 = r2[q2 + 4], h3 = r3[q2 + 4];
                acc4(aL0, l0); acc4(aL1, l1); acc4(aH0, h0); acc4(aH1, h1);
                acc4(aL0, l2); acc4(aL1, l3); acc4(aH0, h2); acc4(aH1, h3);
            }
            for (; p < p1; ++p) {
                const float4* r = ea4 + (size_t)pool[p] * 8;
                float4 l = r[q2], h = r[q2 + 4];
                acc4(aL0, l); acc4(aH0, h);
            }
            acc4(aL0, aL1); acc4(aH0, aH1);
        }
        // write agg rows into swizzled LDS (zeros for out-of-range nodes)
        uint2 lo, hi;
        lo.x = (unsigned)f2bf(aL0.x) | ((unsigned)f2bf(aL0.y) << 16);
        lo.y = (unsigned)f2bf(aL0.z) | ((unsigned)f2bf(aL0.w) << 16);
        hi.x = (unsigned)f2bf(aH0.x) | ((unsigned)f2bf(aH0.y) << 16);
        hi.y = (unsigned)f2bf(aH0.z) | ((unsigned)f2bf(aH0.w) << 16);
        int swz = (g & 7) << 4;
        *(uint2*)(sAgg + ((g * 64 + q2 * 8) ^ swz))       = lo;
        *(uint2*)(sAgg + ((g * 64 + (q2 + 4) * 8) ^ swz)) = hi;
    }

    // ---- hx GEMM: A-frags from global x, B-frags from global WxT (L2-hot)
    int lrow = (w << 4) + col;
    int grow = node0 + lrow;
    bool rok = grow < N;
    int srow = node0 + (w << 4) + m * 4;

    {
        const float* xr = x + (size_t)grow * 128 + m * 8;
        bf16x8 ax[4];
        #pragma unroll
        for (int kk = 0; kk < 4; ++kk) {
            float4 p0 = {0.f,0.f,0.f,0.f}, p1 = {0.f,0.f,0.f,0.f};
            if (rok) {
                p0 = *(const float4*)(xr + kk * 32);
                p1 = *(const float4*)(xr + kk * 32 + 4);
            }
            bf16x8 a;
            a[0] = (short)f2bf(p0.x); a[1] = (short)f2bf(p0.y);
            a[2] = (short)f2bf(p0.z); a[3] = (short)f2bf(p0.w);
            a[4] = (short)f2bf(p1.x); a[5] = (short)f2bf(p1.y);
            a[6] = (short)f2bf(p1.z); a[7] = (short)f2bf(p1.w);
            ax[kk] = a;
        }

        #pragma unroll
        for (int half = 0; half < 2; ++half) {
            f32x4 acc[4];
            #pragma unroll
            for (int ct = 0; ct < 4; ++ct) {
                int c8 = half * 4 + ct;
                float bv = bx[c8 * 16 + col];
                acc[ct] = (f32x4){bv, bv, bv, bv};
            }
            #pragma unroll
            for (int ct = 0; ct < 4; ++ct) {
                int c8 = half * 4 + ct;
                const unsigned short* brow = wxt + (size_t)(c8 * 16 + col) * 128;
                #pragma unroll
                for (int kk = 0; kk < 4; ++kk) {
                    bf16x8 bfrag = *(const bf16x8*)(brow + kk * 32 + m * 8);
                    acc[ct] = __builtin_amdgcn_mfma_f32_16x16x32_bf16(ax[kk], bfrag, acc[ct], 0, 0, 0);
                }
            }
            #pragma unroll
            for (int r = 0; r < 4; ++r) {
                if (srow + r < N) {
                    float* orow = out + (size_t)(srow + r) * 256 + col + half * 64;
                    #pragma unroll
                    for (int ct = 0; ct < 4; ++ct)
                        orow[ct * 16] = acc[ct][r];
                }
            }
        }
    }

    __syncthreads();    // sAgg complete

    // ---- he GEMM: [128,32] @ We + be -> out[:,128:256]
    {
        bf16x8 aa = *(const bf16x8*)(sAgg + ((lrow * 64 + m * 16) ^ ((lrow & 7) << 4)));

        f32x4 acc[8];
        #pragma unroll
        for (int ct = 0; ct < 8; ++ct) {
            float bv = be[ct * 16 + col];
            acc[ct] = (f32x4){bv, bv, bv, bv};
        }
        #pragma unroll
        for (int ct = 0; ct < 8; ++ct) {
            bf16x8 bwe = *(const bf16x8*)(wet + (size_t)(ct * 16 + col) * 32 + m * 8);
            acc[ct] = __builtin_amdgcn_mfma_f32_16x16x32_bf16(aa, bwe, acc[ct], 0, 0, 0);
        }

        #pragma unroll
        for (int r = 0; r < 4; ++r) {
            if (srow + r < N) {
                float* orow = out + (size_t)(srow + r) * 256 + 128 + col;
                #pragma unroll
                for (int ct = 0; ct < 8; ++ct)
                    orow[ct * 16] = acc[ct][r];
            }
        }
    }
}

// ---------- fallback: atomic scatter + convert + full GEMM ----------
__global__ __launch_bounds__(256) void scatter_kernel(
    const float4* __restrict__ ea4, const int* __restrict__ src,
    float* __restrict__ agg, int nquads)
{
    int t = blockIdx.x * blockDim.x + threadIdx.x;
    if (t >= nquads) return;
    int e = t >> 3, q = t & 7;
    float4 v = ea4[t];
    int node = src[e];
    float* dst = agg + (size_t)node * 32 + q * 4;
    atomicAdd(dst + 0, v.x); atomicAdd(dst + 1, v.y);
    atomicAdd(dst + 2, v.z); atomicAdd(dst + 3, v.w);
}

__global__ __launch_bounds__(256) void cvt_kernel(
    const float* __restrict__ agg, unsigned short* __restrict__ aggbf, int n)
{
    int t = blockIdx.x * blockDim.x + threadIdx.x;
    if (t < n) aggbf[t] = f2bf(agg[t]);
}

__global__ __launch_bounds__(512, 4) void mfma_gemm_full(
    const float* __restrict__ x, const unsigned short* __restrict__ aggbf,
    const float* __restrict__ Wx, const float* __restrict__ bx,
    const float* __restrict__ We, const float* __restrict__ be,
    float* __restrict__ out, int N, int ntiles)
{
    __shared__ char sWxT[128 * 256];
    __shared__ char sWeT[128 * 64];
    __shared__ char sX[128 * 256];
    __shared__ char sA[128 * 64];

    int tid = threadIdx.x;
    int lane = tid & 63, w = tid >> 6;
    int col = lane & 15, m = lane >> 4;

    for (int i = tid; i < 128 * 128; i += 512) {
        int k = i >> 7, j = i & 127;
        *(unsigned short*)(sWxT + j * 256 + ((k * 2) ^ ((j & 7) << 4))) = f2bf(Wx[i]);
    }
    for (int i = tid; i < 32 * 128; i += 512) {
        int k = i >> 7, j = i & 127;
        *(unsigned short*)(sWeT + j * 64 + ((k * 2) ^ ((j & 3) << 4))) = f2bf(We[i]);
    }
    float bxv[8], bev[8];
    #pragma unroll
    for (int ct = 0; ct < 8; ++ct) {
        bxv[ct] = bx[ct * 16 + col];
        bev[ct] = be[ct * 16 + col];
    }

    int lrow = (w << 4) + col;
    int swzA = (lrow & 7) << 4;

    for (int t = blockIdx.x; t < ntiles; t += gridDim.x) {
        int rbase_t = t << 7;
        __syncthreads();

        for (int i = tid; i < 128 * 32; i += 512) {
            int row = i >> 5, c4 = i & 31;
            int gr = rbase_t + row;
            float4 v = {0.f, 0.f, 0.f, 0.f};
            if (gr < N) v = *(const float4*)(x + (size_t)gr * 128 + c4 * 4);
            uint2 uu;
            uu.x = (unsigned)f2bf(v.x) | ((unsigned)f2bf(v.y) << 16);
            uu.y = (unsigned)f2bf(v.z) | ((unsigned)f2bf(v.w) << 16);
            *(uint2*)(sX + ((row * 256 + c4 * 8) ^ ((row & 7) << 4))) = uu;
        }
        {
            int row = tid >> 2, mm = tid & 3;
            int gr = rbase_t + row;
            bf16x8 av = {0, 0, 0, 0, 0, 0, 0, 0};
            if (gr < N) av = *(const bf16x8*)(aggbf + (size_t)gr * 32 + mm * 8);
            *(bf16x8*)(sA + ((row * 64 + mm * 16) ^ ((row & 7) << 4))) = av;
        }
        __syncthreads();

        bf16x8 ax[4];
        #pragma unroll
        for (int kk = 0; kk < 4; ++kk)
            ax[kk] = *(const bf16x8*)(sX + lrow * 256 + ((kk * 64 + m * 16) ^ swzA));
        bf16x8 aa = *(const bf16x8*)(sA + ((lrow * 64 + m * 16) ^ swzA));

        int srow = rbase_t + (w << 4) + m * 4;

        #pragma unroll
        for (int half = 0; half < 2; ++half) {
            f32x4 acc[8];
            #pragma unroll
            for (int ct = 0; ct < 4; ++ct) {
                int c8 = half * 4 + ct;
                acc[ct]     = (f32x4){bxv[c8], bxv[c8], bxv[c8], bxv[c8]};
                acc[4 + ct] = (f32x4){bev[c8], bev[c8], bev[c8], bev[c8]};
            }
            #pragma unroll
            for (int ct = 0; ct < 4; ++ct) {
                int c8 = half * 4 + ct;
                const char* brow = sWxT + (c8 * 16 + col) * 256;
                int swz = (col & 7) << 4;
                #pragma unroll
                for (int kk = 0; kk < 4; ++kk) {
                    bf16x8 bfrag = *(const bf16x8*)(brow + ((kk * 64 + m * 16) ^ swz));
                    acc[ct] = __builtin_amdgcn_mfma_f32_16x16x32_bf16(ax[kk], bfrag, acc[ct], 0, 0, 0);
                }
                bf16x8 bwe = *(const bf16x8*)(sWeT + (c8 * 16 + col) * 64 + ((m * 16) ^ ((col & 3) << 4)));
                acc[4 + ct] = __builtin_amdgcn_mfma_f32_16x16x32_bf16(aa, bwe, acc[4 + ct], 0, 0, 0);
            }
            #pragma unroll
            for (int r = 0; r < 4; ++r) {
                if (srow + r < N) {
                    float* orow = out + (size_t)(srow + r) * 256 + col + half * 64;
                    #pragma unroll
                    for (int ct = 0; ct < 4; ++ct) {
                        orow[ct * 16]       = acc[ct][r];
                        orow[128 + ct * 16] = acc[4 + ct][r];
                    }
                }
            }
        }
    }
}

extern "C" void kernel_launch(void* const* d_in, const int* in_sizes, int n_in,
                              void* d_out, int out_size, void* d_ws, size_t ws_size,
                              hipStream_t stream) {
    const float* x          = (const float*)d_in[0];
    const int*   edge_index = (const int*)d_in[1];   // [2,E] flat; row 0 = src
    const float* edge_attr  = (const float*)d_in[2];
    const float* Wx         = (const float*)d_in[3];
    const float* bx         = (const float*)d_in[4];
    const float* We         = (const float*)d_in[5];
    const float* be         = (const float*)d_in[6];
    float* out = (float*)d_out;

    int N = in_sizes[0] / 128;
    int E = in_sizes[2] / 32;
    int nb = (N + BSIZE - 1) >> BSHIFT;
    int ntiles = (N + 127) >> 7;

    char* ws = (char*)d_ws;
    size_t wxtBytes   = 128 * 128 * 2;               // 32 KB
    size_t wetBytes   = 128 * 32 * 2;                // 8 KB
    size_t aggbfBytes = ((size_t)N * 32 * 2 + 255) & ~255ull;
    size_t segsBytes  = ((size_t)nb * SEG_CAP * 4 + 255) & ~255ull;
    size_t gcntBytes  = ((size_t)(nb + 1) * 4 + 255) & ~255ull;
    size_t spillBytes = (size_t)SPILL_CAP * 8;
    size_t need = wxtBytes + wetBytes + aggbfBytes + segsBytes + gcntBytes + spillBytes;

    unsigned short* wxt   = (unsigned short*)ws;
    unsigned short* wet   = (unsigned short*)(ws + wxtBytes);
    unsigned short* aggbf = (unsigned short*)(ws + wxtBytes + wetBytes);

    if (ws_size >= need && nb <= NBMAX) {
        char* p = ws + wxtBytes + wetBytes + aggbfBytes;
        unsigned* segs  = (unsigned*)p;
        int* gcnt       = (int*)(p + segsBytes);
        int* spillcnt   = gcnt + nb;
        int2* spill     = (int2*)(p + segsBytes + gcntBytes);

        hipMemsetAsync(gcnt, 0, (size_t)(nb + 1) * 4, stream);
        prep_kernel<<<64, 256, 0, stream>>>(Wx, We, wxt, wet);
        int nblkA = (E + CHUNK_A - 1) / CHUNK_A;
        binA_kernel<<<nblkA, 512, 0, stream>>>(edge_index, E, nb, segs, gcnt, spill, spillcnt);
        fused_kernel<<<nb, 512, 0, stream>>>(segs, gcnt, spill, spillcnt,
                                             (const float4*)edge_attr, x,
                                             wxt, bx, wet, be, out, N);
    } else {
        float* aggf = (float*)(ws + wxtBytes + wetBytes + aggbfBytes);
        hipMemsetAsync(aggf, 0, (size_t)N * 32 * 4, stream);
        int nq = E * 8;
        scatter_kernel<<<(nq + 255) / 256, 256, 0, stream>>>(
            (const float4*)edge_attr, edge_index, aggf, nq);
        cvt_kernel<<<(N * 32 + 255) / 256, 256, 0, stream>>>(aggf, aggbf, N * 32);
        int g = ntiles < 512 ? ntiles : 512;
        mfma_gemm_full<<<g, 512, 0, stream>>>(x, aggbf, Wx, bx, We, be, out, N, ntiles);
    }
}

// Round 14
// 141.624 us; speedup vs baseline: 1.2934x; 1.1372x over previous
//
#include <hip/hip_runtime.h>

// out[N,256] = concat( x[N,128] @ Wx[128,128] + bx,
//                      segsum(edge_attr by src)[N,32] @ We[32,128] + be )
//
// Pipeline:
//   binA: bucket packed (edge_id<<7 | node&127) by src>>7 (128-node buckets)
//   mega: grid of 2*nb blocks, alternating two specializations:
//     even: gather+he for bucket bid/2  (CSR in LDS -> register gather ->
//           he MFMA -> out[:,128:256])         [latency-bound]
//     odd:  hx GEMM for tile bid/2 (x@Wx+bx -> out[:,0:128])  [compute-bound]
//   Block-level mixing lets the CU overlap hx's MFMA/stream work with the
//   gather blocks' random-read latency (R10 showed wave-level mixing fails;
//   all waves of a block finish gathering simultaneously).

#define BSHIFT    7
#define BSIZE     128
#define NBMAX     1024
#define SEG_CAP   3584    // pairs per bucket (mean ~2046, sigma ~45, +34 sigma)
#define POOL_SZ   3648
#define CHUNK_A   8192
#define SPILL_CAP 65536

typedef short bf16x8 __attribute__((ext_vector_type(8)));
typedef float f32x4  __attribute__((ext_vector_type(4)));

__device__ __forceinline__ unsigned short f2bf(float f) {
    union { float f; unsigned u; } c; c.f = f;
    unsigned u = c.u;
    u += 0x7FFF + ((u >> 16) & 1);          // round-to-nearest-even
    return (unsigned short)(u >> 16);
}

__device__ __forceinline__ void acc4(float4& a, const float4 v) {
    a.x += v.x; a.y += v.y; a.z += v.z; a.w += v.w;
}

// ---------- Pass A: bucket edges (packed 4B pairs) ----------
__global__ __launch_bounds__(512) void binA_kernel(
    const int* __restrict__ src, int E, int nb,
    unsigned* __restrict__ segs, int* __restrict__ gcnt,
    int2* __restrict__ spill, int* __restrict__ spillcnt)
{
    __shared__ unsigned pool[CHUNK_A];      // 32 KB
    __shared__ int hist[NBMAX];
    __shared__ int offs[NBMAX];
    __shared__ int lcur[NBMAX];
    __shared__ int gbase[NBMAX];
    __shared__ int gallow[NBMAX];
    __shared__ int wsum[8];

    int tid = threadIdx.x;
    int base = blockIdx.x * CHUNK_A;

    for (int i = tid; i < NBMAX; i += 512) hist[i] = 0;
    __syncthreads();

    int srcv[CHUNK_A / 512];
    #pragma unroll
    for (int u = 0; u < CHUNK_A / 512; ++u) {
        int e = base + tid + u * 512;
        int s = (e < E) ? src[e] : -1;
        srcv[u] = s;
        if (s >= 0) atomicAdd(&hist[s >> BSHIFT], 1);
    }
    __syncthreads();

    // block exclusive scan: each thread owns buckets 2t, 2t+1
    {
        int t2 = tid * 2;
        int c0 = hist[t2], c1 = hist[t2 + 1];
        int s = c0 + c1;
        int lane = tid & 63, wid = tid >> 6;
        int ws = s;
        #pragma unroll
        for (int d = 1; d < 64; d <<= 1) {
            int t = __shfl_up(ws, d);
            if (lane >= d) ws += t;
        }
        if (lane == 63) wsum[wid] = ws;
        __syncthreads();
        int woff = 0;
        #pragma unroll
        for (int w = 0; w < 8; ++w) if (w < wid) woff += wsum[w];
        int ex = woff + ws - s;
        offs[t2] = ex;          lcur[t2] = ex;
        offs[t2 + 1] = ex + c0; lcur[t2 + 1] = ex + c0;
    }
    __syncthreads();

    {
        int t2 = tid * 2;
        #pragma unroll
        for (int u = 0; u < 2; ++u) {
            int b = t2 + u;
            if (b < nb) {
                int cnt = hist[b];
                int b0 = cnt ? atomicAdd(&gcnt[b], cnt) : 0;
                gbase[b] = b0;
                int allow = SEG_CAP - b0;
                if (allow < 0) allow = 0;
                if (allow > cnt) allow = cnt;
                gallow[b] = allow;
            }
        }
    }
    __syncthreads();

    #pragma unroll
    for (int u = 0; u < CHUNK_A / 512; ++u) {
        int s = srcv[u];
        if (s >= 0) {
            int e = base + tid + u * 512;
            int b = s >> BSHIFT;
            int p = atomicAdd(&lcur[b], 1);
            pool[p] = ((unsigned)e << BSHIFT) | (unsigned)(s & (BSIZE - 1));
        }
    }
    __syncthreads();

    int wid = tid >> 6, lane = tid & 63;
    for (int b = wid; b < nb; b += 8) {
        int cnt = hist[b];
        int off = offs[b];
        int allow = gallow[b];
        unsigned* dst = segs + (size_t)b * SEG_CAP + gbase[b];
        for (int i = lane; i < allow; i += 64)
            dst[i] = pool[off + i];
        int excess = cnt - allow;
        if (excess > 0) {                 // never in practice
            int sb;
            if (lane == 0) sb = atomicAdd(spillcnt, excess);
            sb = __shfl(sb, 0);
            for (int i = lane; i < excess; i += 64) {
                int sp = sb + i;
                if (sp < SPILL_CAP) {
                    unsigned pv = pool[off + allow + i];
                    spill[sp] = make_int2((int)(pv >> BSHIFT),
                                          (b << BSHIFT) | (int)(pv & (BSIZE - 1)));
                }
            }
        }
    }
}

// ---------- mega: even blocks gather+he, odd blocks hx ----------
__global__ __launch_bounds__(512, 4) void mega_kernel(
    const unsigned* __restrict__ segs, const int* __restrict__ gcnt,
    const int2* __restrict__ spill, const int* __restrict__ spillcnt,
    const float4* __restrict__ ea4, const float* __restrict__ x,
    const float* __restrict__ Wx, const float* __restrict__ bx,
    const float* __restrict__ We, const float* __restrict__ be,
    float* __restrict__ out, int N)
{
    __shared__ __align__(16) char smem[32768];

    int tid = threadIdx.x;
    int bid = blockIdx.x;
    int idx = bid >> 1;
    int lane = tid & 63, w = tid >> 6;
    int col = lane & 15, m = lane >> 4;
    int node0 = idx << BSHIFT;
    int srow = node0 + (w << 4) + m * 4;
    int lrow = (w << 4) + col;

    if ((bid & 1) == 0) {
        // ================= gather + he path =================
        int* pool   = (int*)smem;                    // 14592 B
        int* counts = (int*)(smem + 14592);          //   512 B
        int* starts = (int*)(smem + 15104);          //   516 B
        int* cursor = (int*)(smem + 15624);          //   512 B
        char* sAgg  = smem + 16384;                  //  8192 B
        char* sWeT  = smem + 24576;                  //  8192 B

        int b = idx;
        if (tid < BSIZE) counts[tid] = 0;
        // stage We^T (swizzled bf16)
        for (int i = tid; i < 32 * 128; i += 512) {
            int k = i >> 7, j = i & 127;
            *(unsigned short*)(sWeT + j * 64 + ((k * 2) ^ ((j & 3) << 4))) = f2bf(We[i]);
        }
        __syncthreads();

        int segn = gcnt[b]; if (segn > SEG_CAP) segn = SEG_CAP;
        const unsigned* seg = segs + (size_t)b * SEG_CAP;
        int nsp = *spillcnt; if (nsp > SPILL_CAP) nsp = SPILL_CAP;

        // count
        for (int i = tid; i < segn; i += 512)
            atomicAdd(&counts[seg[i] & (BSIZE - 1)], 1);
        if (nsp)
            for (int i = tid; i < nsp; i += 512) {
                int2 p = spill[i];
                if ((p.y >> BSHIFT) == b) atomicAdd(&counts[p.y & (BSIZE - 1)], 1);
            }
        __syncthreads();

        // exclusive scan over 128 counters (wave 0, 2 per lane)
        if (tid < 64) {
            int c0 = counts[tid * 2], c1 = counts[tid * 2 + 1];
            int s = c0 + c1;
            int ws = s;
            #pragma unroll
            for (int d = 1; d < 64; d <<= 1) {
                int t = __shfl_up(ws, d);
                if (tid >= d) ws += t;
            }
            int ex = ws - s;
            starts[tid * 2] = ex;          cursor[tid * 2] = ex;
            starts[tid * 2 + 1] = ex + c0; cursor[tid * 2 + 1] = ex + c0;
            if (tid == 63) starts[BSIZE] = ws;
        }
        __syncthreads();

        // fill grouped edge-id pool
        for (int i = tid; i < segn; i += 512) {
            unsigned pe = seg[i];
            int pos = atomicAdd(&cursor[pe & (BSIZE - 1)], 1);
            if (pos < POOL_SZ) pool[pos] = (int)(pe >> BSHIFT);
        }
        if (nsp)
            for (int i = tid; i < nsp; i += 512) {
                int2 p = spill[i];
                if ((p.y >> BSHIFT) == b) {
                    int pos = atomicAdd(&cursor[p.y & (BSIZE - 1)], 1);
                    if (pos < POOL_SZ) pool[pos] = p.x;
                }
            }
        __syncthreads();

        // register gather: 4 thr/node, quads q2,q2+4, 4-deep unroll
        {
            int g = tid >> 2, q2 = tid & 3;
            int node = node0 + g;
            float4 aL0 = {0.f,0.f,0.f,0.f}, aL1 = {0.f,0.f,0.f,0.f};
            float4 aH0 = {0.f,0.f,0.f,0.f}, aH1 = {0.f,0.f,0.f,0.f};
            if (node < N) {
                int p0 = starts[g], p1 = starts[g + 1];
                if (p1 > POOL_SZ) p1 = POOL_SZ;
                int p = p0;
                for (; p + 4 <= p1; p += 4) {
                    int e0 = pool[p], e1 = pool[p + 1], e2 = pool[p + 2], e3 = pool[p + 3];
                    const float4* r0 = ea4 + (size_t)e0 * 8;
                    const float4* r1 = ea4 + (size_t)e1 * 8;
                    const float4* r2 = ea4 + (size_t)e2 * 8;
                    const float4* r3 = ea4 + (size_t)e3 * 8;
                    float4 l0 = r0[q2],     l1 = r1[q2],     l2 = r2[q2],     l3 = r3[q2];
                    float4 h0 = r0[q2 + 4], h1 = r1[q2 + 4], h2 = r2[q2 + 4], h3 = r3[q2 + 4];
                    acc4(aL0, l0); acc4(aL1, l1); acc4(aH0, h0); acc4(aH1, h1);
                    acc4(aL0, l2); acc4(aL1, l3); acc4(aH0, h2); acc4(aH1, h3);
                }
                for (; p < p1; ++p) {
                    const float4* r = ea4 + (size_t)pool[p] * 8;
                    float4 l = r[q2], h = r[q2 + 4];
                    acc4(aL0, l); acc4(aH0, h);
                }
                acc4(aL0, aL1); acc4(aH0, aH1);
            }
            uint2 lo, hi;
            lo.x = (unsigned)f2bf(aL0.x) | ((unsigned)f2bf(aL0.y) << 16);
            lo.y = (unsigned)f2bf(aL0.z) | ((unsigned)f2bf(aL0.w) << 16);
            hi.x = (unsigned)f2bf(aH0.x) | ((unsigned)f2bf(aH0.y) << 16);
            hi.y = (unsigned)f2bf(aH0.z) | ((unsigned)f2bf(aH0.w) << 16);
            int swz = (g & 7) << 4;
            *(uint2*)(sAgg + ((g * 64 + q2 * 8) ^ swz))       = lo;
            *(uint2*)(sAgg + ((g * 64 + (q2 + 4) * 8) ^ swz)) = hi;
        }
        __syncthreads();

        // he MFMA: [128,32] @ We + be -> out[:,128:256]
        {
            bf16x8 aa = *(const bf16x8*)(sAgg + ((lrow * 64 + m * 16) ^ ((lrow & 7) << 4)));

            f32x4 acc[8];
            #pragma unroll
            for (int ct = 0; ct < 8; ++ct) {
                float bv = be[ct * 16 + col];
                acc[ct] = (f32x4){bv, bv, bv, bv};
            }
            #pragma unroll
            for (int ct = 0; ct < 8; ++ct) {
                bf16x8 bwe = *(const bf16x8*)(sWeT + (ct * 16 + col) * 64 + ((m * 16) ^ ((col & 3) << 4)));
                acc[ct] = __builtin_amdgcn_mfma_f32_16x16x32_bf16(aa, bwe, acc[ct], 0, 0, 0);
            }
            #pragma unroll
            for (int r = 0; r < 4; ++r) {
                if (srow + r < N) {
                    float* orow = out + (size_t)(srow + r) * 256 + 128 + col;
                    #pragma unroll
                    for (int ct = 0; ct < 8; ++ct)
                        orow[ct * 16] = acc[ct][r];
                }
            }
        }
    } else {
        // ================= hx path =================
        char* sWxT = smem;                           // 32768 B

        // stage Wx^T (swizzled bf16)
        for (int i = tid; i < 128 * 128; i += 512) {
            int k = i >> 7, j = i & 127;
            *(unsigned short*)(sWxT + j * 256 + ((k * 2) ^ ((j & 7) << 4))) = f2bf(Wx[i]);
        }
        __syncthreads();

        int grow = node0 + lrow;
        bool rok = grow < N;

        const float* xr = x + (size_t)grow * 128 + m * 8;
        bf16x8 ax[4];
        #pragma unroll
        for (int kk = 0; kk < 4; ++kk) {
            float4 p0 = {0.f,0.f,0.f,0.f}, p1 = {0.f,0.f,0.f,0.f};
            if (rok) {
                p0 = *(const float4*)(xr + kk * 32);
                p1 = *(const float4*)(xr + kk * 32 + 4);
            }
            bf16x8 a;
            a[0] = (short)f2bf(p0.x); a[1] = (short)f2bf(p0.y);
            a[2] = (short)f2bf(p0.z); a[3] = (short)f2bf(p0.w);
            a[4] = (short)f2bf(p1.x); a[5] = (short)f2bf(p1.y);
            a[6] = (short)f2bf(p1.z); a[7] = (short)f2bf(p1.w);
            ax[kk] = a;
        }

        #pragma unroll
        for (int half = 0; half < 2; ++half) {
            f32x4 acc[4];
            #pragma unroll
            for (int ct = 0; ct < 4; ++ct) {
                int c8 = half * 4 + ct;
                float bv = bx[c8 * 16 + col];
                acc[ct] = (f32x4){bv, bv, bv, bv};
            }
            #pragma unroll
            for (int ct = 0; ct < 4; ++ct) {
                int c8 = half * 4 + ct;
                const char* brow = sWxT + (c8 * 16 + col) * 256;
                int swz = (col & 7) << 4;
                #pragma unroll
                for (int kk = 0; kk < 4; ++kk) {
                    bf16x8 bfrag = *(const bf16x8*)(brow + ((kk * 64 + m * 16) ^ swz));
                    acc[ct] = __builtin_amdgcn_mfma_f32_16x16x32_bf16(ax[kk], bfrag, acc[ct], 0, 0, 0);
                }
            }
            #pragma unroll
            for (int r = 0; r < 4; ++r) {
                if (srow + r < N) {
                    float* orow = out + (size_t)(srow + r) * 256 + col + half * 64;
                    #pragma unroll
                    for (int ct = 0; ct < 4; ++ct)
                        orow[ct * 16] = acc[ct][r];
                }
            }
        }
    }
}

// ---------- fallback: atomic scatter + convert + full GEMM ----------
__global__ __launch_bounds__(256) void scatter_kernel(
    const float4* __restrict__ ea4, const int* __restrict__ src,
    float* __restrict__ agg, int nquads)
{
    int t = blockIdx.x * blockDim.x + threadIdx.x;
    if (t >= nquads) return;
    int e = t >> 3, q = t & 7;
    float4 v = ea4[t];
    int node = src[e];
    float* dst = agg + (size_t)node * 32 + q * 4;
    atomicAdd(dst + 0, v.x); atomicAdd(dst + 1, v.y);
    atomicAdd(dst + 2, v.z); atomicAdd(dst + 3, v.w);
}

__global__ __launch_bounds__(256) void cvt_kernel(
    const float* __restrict__ agg, unsigned short* __restrict__ aggbf, int n)
{
    int t = blockIdx.x * blockDim.x + threadIdx.x;
    if (t < n) aggbf[t] = f2bf(agg[t]);
}

__global__ __launch_bounds__(512, 4) void mfma_gemm_full(
    const float* __restrict__ x, const unsigned short* __restrict__ aggbf,
    const float* __restrict__ Wx, const float* __restrict__ bx,
    const float* __restrict__ We, const float* __restrict__ be,
    float* __restrict__ out, int N, int ntiles)
{
    __shared__ char sWxT[128 * 256];
    __shared__ char sWeT[128 * 64];
    __shared__ char sX[128 * 256];
    __shared__ char sA[128 * 64];

    int tid = threadIdx.x;
    int lane = tid & 63, w = tid >> 6;
    int col = lane & 15, m = lane >> 4;

    for (int i = tid; i < 128 * 128; i += 512) {
        int k = i >> 7, j = i & 127;
        *(unsigned short*)(sWxT + j * 256 + ((k * 2) ^ ((j & 7) << 4))) = f2bf(Wx[i]);
    }
    for (int i = tid; i < 32 * 128; i += 512) {
        int k = i >> 7, j = i & 127;
        *(unsigned short*)(sWeT + j * 64 + ((k * 2) ^ ((j & 3) << 4))) = f2bf(We[i]);
    }
    float bxv[8], bev[8];
    #pragma unroll
    for (int ct = 0; ct < 8; ++ct) {
        bxv[ct] = bx[ct * 16 + col];
        bev[ct] = be[ct * 16 + col];
    }

    int lrow = (w << 4) + col;
    int swzA = (lrow & 7) << 4;

    for (int t = blockIdx.x; t < ntiles; t += gridDim.x) {
        int rbase_t = t << 7;
        __syncthreads();

        for (int i = tid; i < 128 * 32; i += 512) {
            int row = i >> 5, c4 = i & 31;
            int gr = rbase_t + row;
            float4 v = {0.f, 0.f, 0.f, 0.f};
            if (gr < N) v = *(const float4*)(x + (size_t)gr * 128 + c4 * 4);
            uint2 uu;
            uu.x = (unsigned)f2bf(v.x) | ((unsigned)f2bf(v.y) << 16);
            uu.y = (unsigned)f2bf(v.z) | ((unsigned)f2bf(v.w) << 16);
            *(uint2*)(sX + ((row * 256 + c4 * 8) ^ ((row & 7) << 4))) = uu;
        }
        {
            int row = tid >> 2, mm = tid & 3;
            int gr = rbase_t + row;
            bf16x8 av = {0, 0, 0, 0, 0, 0, 0, 0};
            if (gr < N) av = *(const bf16x8*)(aggbf + (size_t)gr * 32 + mm * 8);
            *(bf16x8*)(sA + ((row * 64 + mm * 16) ^ ((row & 7) << 4))) = av;
        }
        __syncthreads();

        bf16x8 ax[4];
        #pragma unroll
        for (int kk = 0; kk < 4; ++kk)
            ax[kk] = *(const bf16x8*)(sX + lrow * 256 + ((kk * 64 + m * 16) ^ swzA));
        bf16x8 aa = *(const bf16x8*)(sA + ((lrow * 64 + m * 16) ^ swzA));

        int srow = rbase_t + (w << 4) + m * 4;

        #pragma unroll
        for (int half = 0; half < 2; ++half) {
            f32x4 acc[8];
            #pragma unroll
            for (int ct = 0; ct < 4; ++ct) {
                int c8 = half * 4 + ct;
                acc[ct]     = (f32x4){bxv[c8], bxv[c8], bxv[c8], bxv[c8]};
                acc[4 + ct] = (f32x4){bev[c8], bev[c8], bev[c8], bev[c8]};
            }
            #pragma unroll
            for (int ct = 0; ct < 4; ++ct) {
                int c8 = half * 4 + ct;
                const char* brow = sWxT + (c8 * 16 + col) * 256;
                int swz = (col & 7) << 4;
                #pragma unroll
                for (int kk = 0; kk < 4; ++kk) {
                    bf16x8 bfrag = *(const bf16x8*)(brow + ((kk * 64 + m * 16) ^ swz));
                    acc[ct] = __builtin_amdgcn_mfma_f32_16x16x32_bf16(ax[kk], bfrag, acc[ct], 0, 0, 0);
                }
                bf16x8 bwe = *(const bf16x8*)(sWeT + (c8 * 16 + col) * 64 + ((m * 16) ^ ((col & 3) << 4)));
                acc[4 + ct] = __builtin_amdgcn_mfma_f32_16x16x32_bf16(aa, bwe, acc[4 + ct], 0, 0, 0);
            }
            #pragma unroll
            for (int r = 0; r < 4; ++r) {
                if (srow + r < N) {
                    float* orow = out + (size_t)(srow + r) * 256 + col + half * 64;
                    #pragma unroll
                    for (int ct = 0; ct < 4; ++ct) {
                        orow[ct * 16]       = acc[ct][r];
                        orow[128 + ct * 16] = acc[4 + ct][r];
                    }
                }
            }
        }
    }
}

extern "C" void kernel_launch(void* const* d_in, const int* in_sizes, int n_in,
                              void* d_out, int out_size, void* d_ws, size_t ws_size,
                              hipStream_t stream) {
    const float* x          = (const float*)d_in[0];
    const int*   edge_index = (const int*)d_in[1];   // [2,E] flat; row 0 = src
    const float* edge_attr  = (const float*)d_in[2];
    const float* Wx         = (const float*)d_in[3];
    const float* bx         = (const float*)d_in[4];
    const float* We         = (const float*)d_in[5];
    const float* be         = (const float*)d_in[6];
    float* out = (float*)d_out;

    int N = in_sizes[0] / 128;
    int E = in_sizes[2] / 32;
    int nb = (N + BSIZE - 1) >> BSHIFT;
    int ntiles = (N + 127) >> 7;

    char* ws = (char*)d_ws;
    size_t aggbfBytes = ((size_t)N * 32 * 2 + 255) & ~255ull;
    size_t segsBytes  = ((size_t)nb * SEG_CAP * 4 + 255) & ~255ull;
    size_t gcntBytes  = ((size_t)(nb + 1) * 4 + 255) & ~255ull;
    size_t spillBytes = (size_t)SPILL_CAP * 8;
    size_t need = aggbfBytes + segsBytes + gcntBytes + spillBytes;

    unsigned short* aggbf = (unsigned short*)ws;

    if (ws_size >= need && nb <= NBMAX) {
        unsigned* segs  = (unsigned*)(ws + aggbfBytes);
        int* gcnt       = (int*)(ws + aggbfBytes + segsBytes);
        int* spillcnt   = gcnt + nb;
        int2* spill     = (int2*)(ws + aggbfBytes + segsBytes + gcntBytes);

        hipMemsetAsync(gcnt, 0, (size_t)(nb + 1) * 4, stream);
        int nblkA = (E + CHUNK_A - 1) / CHUNK_A;
        binA_kernel<<<nblkA, 512, 0, stream>>>(edge_index, E, nb, segs, gcnt, spill, spillcnt);
        mega_kernel<<<2 * nb, 512, 0, stream>>>(segs, gcnt, spill, spillcnt,
                                                (const float4*)edge_attr, x,
                                                Wx, bx, We, be, out, N);
    } else {
        float* aggf = (float*)(ws + aggbfBytes);
        hipMemsetAsync(aggf, 0, (size_t)N * 32 * 4, stream);
        int nq = E * 8;
        scatter_kernel<<<(nq + 255) / 256, 256, 0, stream>>>(
            (const float4*)edge_attr, edge_index, aggf, nq);
        cvt_kernel<<<(N * 32 + 255) / 256, 256, 0, stream>>>(aggf, aggbf, N * 32);
        int g = ntiles < 512 ? ntiles : 512;
        mfma_gemm_full<<<g, 512, 0, stream>>>(x, aggbf, Wx, bx, We, be, out, N, ntiles);
    }
}